// Round 2
// baseline (80.790 us; speedup 1.0000x reference)
//
#include <hip/hip_runtime.h>
#include <math.h>
#include <float.h>

#define EPS 1e-6f
#define THRESHOLD 0.5f

#define NB 16
#define NPOLY 16
#define NVERT 200
#define NSEG_PER_POLY 199
#define NSEG (NPOLY * NSEG_PER_POLY)   // 3184 segments per batch
#define NAGENT 10
#define NPPA 30                        // points per agent
#define NPTB (NAGENT * NPPA)           // 300
#define NTHREADS 512
#define NCHUNK 128                     // segment chunks (t & 127)
#define PSLOT 8                        // point slots per thread (4 groups x 8 >= 30)

// ---------------------------------------------------------------------------
// R8: single fused kernel, zero workspace, zero atomics.
//
// Evidence (R7 rocprof): top-5 dispatches are ALL the harness's 256 MiB
// workspace re-poison fills (~40.3 us @ 84% HBM peak) — an untouchable floor
// inside the timed region. Our kernels are the other ~40 us, and R7's 2x
// LDS-read reduction moved nothing (79.6 -> 80.7), falsifying the LDS-pipe
// theory. The residual is structural: 2 dispatches, part[] HBM round-trip,
// latency-bound final_kernel, per-block barrier/prologue latency x1024.
//
// New structure: 1 block per (batch, agent) = 160 blocks x 512 threads.
//   thread = (pg, sc): pg = point-group (8 of the agent's 30 points held in
//   registers, statically unrolled), sc = 1-of-128 segment chunk.
//   Main loop: s = sc, sc+128, ... (~25 segs) — 64 consecutive lanes read 64
//   consecutive segments straight from global (coalesced, L2-cached; no LDS,
//   no barrier). Per-segment precompute (incl. both exact IEEE divides)
//   amortizes over 8 points.
//   Reduce: 6-step __shfl_xor butterfly (64 lanes = 64 chunks) -> tiny LDS
//   combine of the pg's two waves -> per-point epilogue -> thread 0 sums 30
//   vals -> out[b][agent] direct store. No part[], no final kernel, no
//   atomics, no zero-init (each out element owned by exactly one block).
//
// Exactness: identical formulas to validated R7 (absmax 0.0):
//   slope_eps = evy/(evx+EPS)+EPS and inv_esq = 1/(esq+EPS) as exact IEEE;
//   crossing = rcp fast path, band err = 2e-6|q| + (1e-6|sx| + 1e-30),
//   borderline -> bit-exact IEEE-div fallback; cond_y XOR-form exact;
//   distance path (rcp-free, fma/med3) ulp-tolerant, feeds min only.
// ---------------------------------------------------------------------------
__global__ __launch_bounds__(NTHREADS) void fused_kernel(
    const float* __restrict__ points,
    const float* __restrict__ polys,
    float* __restrict__ out)
{
    __shared__ float redmin[8][PSLOT];   // [wave][slot]
    __shared__ int   redcnt[8][PSLOT];
    __shared__ float vals[NPPA];

    const int agent = blockIdx.x;        // 0..9
    const int b     = blockIdx.y;        // 0..15
    const int t     = threadIdx.x;       // 0..511
    const int sc    = t & (NCHUNK - 1);  // segment chunk, wave-contiguous
    const int pg    = t >> 7;            // point group 0..3 (uniform per wave)
    const int wv    = t >> 6;            // wave 0..7
    const int lane  = t & 63;

    // ---- this thread's 8 points, in registers (slots past 29 duplicate
    //      point 29; computed but never read back) ----
    float px[PSLOT], py[PSLOT], mins[PSLOT];
    int   cnts[PSLOT];
    const float2* pbase = (const float2*)points + ((size_t)b * NPTB + agent * NPPA);
    #pragma unroll
    for (int k = 0; k < PSLOT; ++k) {
        int j = pg * PSLOT + k;
        if (j > NPPA - 1) j = NPPA - 1;
        const float2 p = pbase[j];       // wave-uniform addr -> scalar/broadcast
        px[k] = p.x;  py[k] = p.y;
        mins[k] = FLT_MAX;  cnts[k] = 0;
    }

    const float2* pol = (const float2*)polys + (size_t)b * NPOLY * NVERT;

    // ---- main loop: ~25 segments per thread, no LDS, no barrier ----
    for (int s = sc; s < NSEG; s += NCHUNK) {
        const int m    = s / NSEG_PER_POLY;       // magic-mul
        const int v    = s - m * NSEG_PER_POLY;
        const int base = m * NVERT + v;           // = s + m: lane-consecutive
        const float2 S = pol[base];
        const float2 E = pol[base + 1];
        const float sx  = S.x, sy = S.y, ey = E.y;
        const float evx = E.x - sx;
        const float evy = ey - sy;
        const float esq = fmaf(evx, evx, evy * evy);
        const float inv_esq   = 1.0f / (esq + EPS);        // exact IEEE
        const float slope_eps = evy / (evx + EPS) + EPS;   // exact IEEE, ref order
        const float inv_slope = __builtin_amdgcn_rcpf(slope_eps);
        const float errS      = fmaf(fabsf(sx), 1e-6f, 1e-30f);

        #pragma unroll
        for (int k = 0; k < PSLOT; ++k) {
            // ---- point-to-segment squared distance (ulp-tolerant) ----
            const float v1x = px[k] - sx;
            const float v1y = py[k] - sy;
            const float dot = fmaf(v1y, evy, v1x * evx);
            const float tt  = __builtin_amdgcn_fmed3f(dot * inv_esq, 0.0f, 1.0f);
            const float dx  = fmaf(-evx, tt, v1x);
            const float dy  = fmaf(-evy, tt, v1y);
            mins[k] = fminf(mins[k], fmaf(dy, dy, dx * dx));

            // ---- even-odd crossing: rcp fast path + exact-div fallback ----
            const bool  cond_y = (sy <= py[k]) != (ey <= py[k]);   // exact
            const float q    = v1y * inv_slope;                    // ~2 ulp
            const float diff = q - v1x;
            const float err  = fmaf(fabsf(q), 2e-6f, errS);
            bool left = diff > 0.0f;
            if (cond_y && !(fabsf(diff) > err)) {
                // rare: decision within rcp noise — replicate ref bit-exactly
                left = (sx + v1y / slope_eps) > px[k];
            }
            cnts[k] += (cond_y && left) ? 1 : 0;
        }
    }

    // ---- stage 1: 64-lane butterfly (64 seg-chunks of this pg) ----
    #pragma unroll
    for (int k = 0; k < PSLOT; ++k) {
        float mn = mins[k];
        int   cc = cnts[k];
        #pragma unroll
        for (int d = 1; d < 64; d <<= 1) {
            mn = fminf(mn, __shfl_xor(mn, d, 64));
            cc += __shfl_xor(cc, d, 64);
        }
        if (lane == 0) { redmin[wv][k] = mn; redcnt[wv][k] = cc; }
    }
    __syncthreads();

    // ---- stage 2: combine the pg's two waves; per-point epilogue ----
    if (t < NPPA) {
        const int jpg = t >> 3, k = t & 7;       // point t -> (group, slot)
        const float mn = fminf(redmin[2 * jpg][k], redmin[2 * jpg + 1][k]);
        const int   cc = redcnt[2 * jpg][k] + redcnt[2 * jpg + 1][k];
        float d = sqrtf(fmaxf(mn, EPS));
        if (cc & 1) d = -d;
        vals[t] = fmaxf(d + THRESHOLD, 0.0f);
    }
    __syncthreads();

    // ---- stage 3: agent sum -> direct store (block owns this out element) ----
    if (t == 0) {
        float ssum = 0.0f;
        #pragma unroll
        for (int j = 0; j < NPPA; ++j) ssum += vals[j];
        out[b * NAGENT + agent] = ssum;
    }
}

extern "C" void kernel_launch(void* const* d_in, const int* in_sizes, int n_in,
                              void* d_out, int out_size, void* d_ws, size_t ws_size,
                              hipStream_t stream) {
    const float* points = (const float*)d_in[0];   // (16,10,30,2)
    const float* polys  = (const float*)d_in[1];   // (16,16,200,2)
    float* out = (float*)d_out;                    // (16,10)

    // d_ws intentionally unused: no partials, no cross-block reduction.
    (void)d_ws; (void)ws_size;

    dim3 grid(NAGENT, NB);                         // 160 blocks x 512 threads
    fused_kernel<<<grid, NTHREADS, 0, stream>>>(points, polys, out);
}